// Round 1
// baseline (247.321 us; speedup 1.0000x reference)
//
#include <hip/hip_runtime.h>
#include <math.h>

#define NN 50001
#define DD 128
#define NE 800000

typedef __attribute__((ext_vector_type(8))) short short8;
typedef __attribute__((ext_vector_type(4))) float floatx4;

__device__ __forceinline__ unsigned short f2bf(float f) {
    unsigned u = __builtin_bit_cast(unsigned, f);
    u += 0x7fffu + ((u >> 16) & 1u);          // round-to-nearest-even
    return (unsigned short)(u >> 16);
}
__device__ __forceinline__ float bf2f(unsigned u16) {
    return __builtin_bit_cast(float, u16 << 16);
}

// K0: W_scale (128x128 f32, [k][j]) -> WT (bf16, [j][k]) for contiguous B-frag loads
__global__ void k_wt(const float* __restrict__ W, unsigned short* __restrict__ WT) {
    int idx = blockIdx.x * blockDim.x + threadIdx.x;
    if (idx < DD * DD) {
        int k = idx >> 7, j = idx & 127;
        WT[j * DD + k] = f2bf(W[idx]);
    }
}

// K1: item_scaled = emb @ W_scale + b_scale, stored bf16. One wave per 16-node tile.
__global__ void __launch_bounds__(256) k_gemm(const float* __restrict__ emb,
        const unsigned short* __restrict__ WT, const float* __restrict__ b_scale,
        unsigned short* __restrict__ item) {
    int wave = blockIdx.x * 4 + (threadIdx.x >> 6);
    int lane = threadIdx.x & 63;
    int base = wave * 16;
    if (base >= NN) return;
    int m = lane & 15, q = lane >> 4;

    // A frags: lane holds A[m][q*8 + ks*32 .. +7], f32 -> bf16 on the fly
    int row = base + m; if (row >= NN) row = NN - 1;
    const float* ap = emb + (long)row * DD + q * 8;
    short8 a[4];
    #pragma unroll
    for (int ks = 0; ks < 4; ks++) {
        const float* p = ap + ks * 32;
        #pragma unroll
        for (int j = 0; j < 8; j++) a[ks][j] = (short)f2bf(p[j]);
    }

    #pragma unroll
    for (int ft = 0; ft < 8; ft++) {
        int col = ft * 16 + m;
        floatx4 acc = {0.f, 0.f, 0.f, 0.f};
        #pragma unroll
        for (int ks = 0; ks < 4; ks++) {
            short8 b = *(const short8*)(WT + col * DD + ks * 32 + q * 8);
            acc = __builtin_amdgcn_mfma_f32_16x16x32_bf16(a[ks], b, acc, 0, 0, 0);
        }
        float bs = b_scale[col];
        #pragma unroll
        for (int r = 0; r < 4; r++) {
            int gr = base + q * 4 + r;   // C/D: col = lane&15, row = (lane>>4)*4 + reg
            if (gr < NN) item[(long)gr * DD + col] = f2bf(acc[r] + bs);
        }
    }
}

// K2: a_src[n] = item[n] . W_att[0:128], a_dst[n] = item[n] . W_att[128:256]
__global__ void __launch_bounds__(256) k_att(const unsigned short* __restrict__ item,
        const float* __restrict__ W_att, float* __restrict__ a_src, float* __restrict__ a_dst) {
    int n = blockIdx.x * 4 + (threadIdx.x >> 6);
    int lane = threadIdx.x & 63;
    if (n >= NN) return;
    unsigned u = *(const unsigned*)(item + (long)n * DD + 2 * lane);
    float f0 = bf2f(u & 0xffffu), f1 = bf2f(u >> 16);
    float s1 = f0 * W_att[2 * lane]      + f1 * W_att[2 * lane + 1];
    float s2 = f0 * W_att[DD + 2 * lane] + f1 * W_att[DD + 2 * lane + 1];
    #pragma unroll
    for (int off = 32; off >= 1; off >>= 1) {
        s1 += __shfl_xor(s1, off, 64);
        s2 += __shfl_xor(s2, off, 64);
    }
    if (lane == 0) { a_src[n] = s1; a_dst[n] = s2; }
}

// K3: per-node segment aggregation (src sorted). One wave per node.
__global__ void __launch_bounds__(256) k_agg(const int* __restrict__ edge,
        const unsigned short* __restrict__ item, const float* __restrict__ a_src,
        const float* __restrict__ a_dst, const float* __restrict__ b_att,
        float* __restrict__ out) {
    int n = blockIdx.x * 4 + (threadIdx.x >> 6);
    int lane = threadIdx.x & 63;
    if (n >= NN) return;

    // binary search segment [start, end) of src == n (lanes redundant, broadcast loads)
    int lo = 0, hi = NE;
    while (lo < hi) { int mid = (lo + hi) >> 1; if (edge[2 * mid] < n) lo = mid + 1; else hi = mid; }
    int start = lo;
    hi = NE;
    while (lo < hi) { int mid = (lo + hi) >> 1; if (edge[2 * mid] <= n) lo = mid + 1; else hi = mid; }
    int end = lo;

    float r0, r1;
    if (end > start) {
        float asrc = a_src[n] + b_att[0];
        float acc0 = 0.f, acc1 = 0.f, ssum = 0.f;
        for (int b = start; b < end; b += 64) {
            int cnt = min(64, end - b);
            int d = 0; float s = 0.f;
            if (lane < cnt) {                 // lanes cooperatively fetch up to 64 edges
                int e = b + lane;
                d = edge[2 * e + 1];
                float att = asrc + a_dst[d];
                att = att >= 0.f ? att : 0.2f * att;
                s = __expf(att - 1.f);
            }
            for (int i = 0; i < cnt; i++) {
                int   di = __shfl(d, i);
                float si = __shfl(s, i);
                unsigned u = *(const unsigned*)(item + (long)di * DD + 2 * lane);
                acc0 += si * bf2f(u & 0xffffu);
                acc1 += si * bf2f(u >> 16);
                ssum += si;
            }
        }
        float inv = 1.f / ssum;
        r0 = 1.f / (1.f + __expf(-acc0 * inv));
        r1 = 1.f / (1.f + __expf(-acc1 * inv));
    } else {
        r0 = r1 = 0.5f;                       // empty segment: sigmoid(0)
    }
    float2 v = make_float2(r0, r1);
    *(float2*)(out + (long)n * DD + 2 * lane) = v;
}

extern "C" void kernel_launch(void* const* d_in, const int* in_sizes, int n_in,
                              void* d_out, int out_size, void* d_ws, size_t ws_size,
                              hipStream_t stream) {
    const int*   edge    = (const int*)d_in[0];
    const float* emb     = (const float*)d_in[1];
    const float* W_scale = (const float*)d_in[2];
    const float* b_scale = (const float*)d_in[3];
    const float* W_att   = (const float*)d_in[4];
    const float* b_att   = (const float*)d_in[5];
    float* out = (float*)d_out;

    char* ws = (char*)d_ws;
    unsigned short* WT    = (unsigned short*)(ws);                       // 32 KB
    float*          a_src = (float*)(ws + 32768);                        // 200192 B
    float*          a_dst = (float*)(ws + 32768 + 200192);               // 200192 B
    unsigned short* item  = (unsigned short*)(ws + 32768 + 2 * 200192);  // 12.8 MB

    int node_blocks = (NN + 3) / 4;          // wave per node, 4 waves/block
    int tile_blocks = ((NN + 15) / 16 + 3) / 4;

    k_wt  <<<64,          256, 0, stream>>>(W_scale, WT);
    k_gemm<<<tile_blocks, 256, 0, stream>>>(emb, WT, b_scale, item);
    k_att <<<node_blocks, 256, 0, stream>>>(item, W_att, a_src, a_dst);
    k_agg <<<node_blocks, 256, 0, stream>>>(edge, item, a_src, a_dst, b_att, out);
}

// Round 2
// 148.942 us; speedup vs baseline: 1.6605x; 1.6605x over previous
//
#include <hip/hip_runtime.h>
#include <math.h>

#define NN 50001
#define DD 128
#define NE 800000

typedef __attribute__((ext_vector_type(8))) short short8;
typedef __attribute__((ext_vector_type(4))) float floatx4;

__device__ __forceinline__ unsigned short f2bf(float f) {
    unsigned u = __builtin_bit_cast(unsigned, f);
    u += 0x7fffu + ((u >> 16) & 1u);          // round-to-nearest-even
    return (unsigned short)(u >> 16);
}
__device__ __forceinline__ float bflo(unsigned u) {   // low 16 bits as bf16 -> f32
    return __builtin_bit_cast(float, u << 16);
}
__device__ __forceinline__ float bfhi(unsigned u) {   // high 16 bits as bf16 -> f32
    return __builtin_bit_cast(float, u & 0xffff0000u);
}

// K0: W_scale (128x128 f32, [k][j]) -> WT (bf16, [j][k]) for contiguous B-frag loads
__global__ void k_wt(const float* __restrict__ W, unsigned short* __restrict__ WT) {
    int idx = blockIdx.x * blockDim.x + threadIdx.x;
    if (idx < DD * DD) {
        int k = idx >> 7, j = idx & 127;
        WT[j * DD + k] = f2bf(W[idx]);
    }
}

// K0b: row_ptr[n] = first edge e with src[e] >= n  (src is sorted).
__global__ void k_rowptr(const int* __restrict__ edge, int* __restrict__ row_ptr) {
    int e = blockIdx.x * blockDim.x + threadIdx.x;
    if (e >= NE) return;
    int s = edge[2 * e];
    if (e == 0) {
        for (int n = 0; n <= s; n++) row_ptr[n] = 0;
    } else {
        int p = edge[2 * (e - 1)];
        for (int n = p + 1; n <= s; n++) row_ptr[n] = e;
    }
    if (e == NE - 1) {
        for (int n = s + 1; n <= NN; n++) row_ptr[n] = NE;
    }
}

// K1: item = emb @ W_scale + b_scale (bf16 out), fused a_src/a_dst = item . W_att halves.
// One wave per 16-node tile.
__global__ void __launch_bounds__(256) k_gemm(const float* __restrict__ emb,
        const unsigned short* __restrict__ WT, const float* __restrict__ b_scale,
        const float* __restrict__ W_att, unsigned short* __restrict__ item,
        float* __restrict__ a_src, float* __restrict__ a_dst) {
    int wave = blockIdx.x * 4 + (threadIdx.x >> 6);
    int lane = threadIdx.x & 63;
    int base = wave * 16;
    if (base >= NN) return;
    int m = lane & 15, q = lane >> 4;

    // A frags: lane holds A[m][q*8 + ks*32 .. +7], f32 -> bf16 on the fly
    int row = base + m; if (row >= NN) row = NN - 1;
    const float* ap = emb + (long)row * DD + q * 8;
    short8 a[4];
    #pragma unroll
    for (int ks = 0; ks < 4; ks++) {
        const float* p = ap + ks * 32;
        #pragma unroll
        for (int j = 0; j < 8; j++) a[ks][j] = (short)f2bf(p[j]);
    }

    float p_src[4] = {0.f, 0.f, 0.f, 0.f};
    float p_dst[4] = {0.f, 0.f, 0.f, 0.f};

    #pragma unroll
    for (int ft = 0; ft < 8; ft++) {
        int col = ft * 16 + m;
        floatx4 acc = {0.f, 0.f, 0.f, 0.f};
        #pragma unroll
        for (int ks = 0; ks < 4; ks++) {
            short8 b = *(const short8*)(WT + col * DD + ks * 32 + q * 8);
            acc = __builtin_amdgcn_mfma_f32_16x16x32_bf16(a[ks], b, acc, 0, 0, 0);
        }
        float bs = b_scale[col];
        float wsrc = W_att[col], wdst = W_att[DD + col];
        #pragma unroll
        for (int r = 0; r < 4; r++) {
            float v = acc[r] + bs;            // C/D: col = lane&15, row = (lane>>4)*4 + reg
            int gr = base + q * 4 + r;
            if (gr < NN) item[(long)gr * DD + col] = f2bf(v);
            p_src[r] += v * wsrc;
            p_dst[r] += v * wdst;
        }
    }
    // reduce over m (lane bits 0..3): rows stay within the q-group
    #pragma unroll
    for (int off = 1; off <= 8; off <<= 1) {
        #pragma unroll
        for (int r = 0; r < 4; r++) {
            p_src[r] += __shfl_xor(p_src[r], off, 64);
            p_dst[r] += __shfl_xor(p_dst[r], off, 64);
        }
    }
    if (m == 0) {
        #pragma unroll
        for (int r = 0; r < 4; r++) {
            int gr = base + q * 4 + r;
            if (gr < NN) { a_src[gr] = p_src[r]; a_dst[gr] = p_dst[r]; }
        }
    }
}

// K2: per-node segment aggregation. One wave per node; 4 edges per inner iteration,
// 16 B gather loads. lane = 16*g + t: group g owns edge j=4i+g, lane covers features t*8..t*8+7.
__global__ void __launch_bounds__(256) k_agg(const int* __restrict__ edge,
        const int* __restrict__ row_ptr, const unsigned short* __restrict__ item,
        const float* __restrict__ a_src, const float* __restrict__ a_dst,
        const float* __restrict__ b_att, float* __restrict__ out) {
    int n = blockIdx.x * 4 + (threadIdx.x >> 6);
    int lane = threadIdx.x & 63;
    if (n >= NN) return;
    int g = lane >> 4, t = lane & 15;

    int start = row_ptr[n], end = row_ptr[n + 1];

    if (end > start) {
        float asrc = a_src[n] + b_att[0];
        float acc[8] = {0.f, 0.f, 0.f, 0.f, 0.f, 0.f, 0.f, 0.f};
        float ssum = 0.f;
        for (int b = start; b < end; b += 64) {
            int cnt = min(64, end - b);
            int d = 0; float s = 0.f;
            if (lane < cnt) {                 // lanes cooperatively score up to 64 edges
                int e = b + lane;
                d = edge[2 * e + 1];
                float att = asrc + a_dst[d];
                att = att >= 0.f ? att : 0.2f * att;
                s = __expf(att - 1.f);
            }
            ssum += s;
            int ngroups = (cnt + 3) >> 2;
            for (int i = 0; i < ngroups; i++) {
                int j = 4 * i + g;            // j < 64 always; j >= cnt has s=0 -> no-op
                float sj = __shfl(s, j);
                int   dj = __shfl(d, j);
                const uint4 u = *(const uint4*)(item + (long)dj * DD + t * 8);
                acc[0] += sj * bflo(u.x); acc[1] += sj * bfhi(u.x);
                acc[2] += sj * bflo(u.y); acc[3] += sj * bfhi(u.y);
                acc[4] += sj * bflo(u.z); acc[5] += sj * bfhi(u.z);
                acc[6] += sj * bflo(u.w); acc[7] += sj * bfhi(u.w);
            }
        }
        // combine the 4 edge-groups (lane bits 4,5)
        #pragma unroll
        for (int off = 16; off <= 32; off <<= 1) {
            #pragma unroll
            for (int k = 0; k < 8; k++) acc[k] += __shfl_xor(acc[k], off, 64);
        }
        #pragma unroll
        for (int off = 1; off < 64; off <<= 1) ssum += __shfl_xor(ssum, off, 64);

        if (g == 0) {
            float inv = 1.f / ssum;
            float4 o0, o1;
            o0.x = 1.f / (1.f + __expf(-acc[0] * inv));
            o0.y = 1.f / (1.f + __expf(-acc[1] * inv));
            o0.z = 1.f / (1.f + __expf(-acc[2] * inv));
            o0.w = 1.f / (1.f + __expf(-acc[3] * inv));
            o1.x = 1.f / (1.f + __expf(-acc[4] * inv));
            o1.y = 1.f / (1.f + __expf(-acc[5] * inv));
            o1.z = 1.f / (1.f + __expf(-acc[6] * inv));
            o1.w = 1.f / (1.f + __expf(-acc[7] * inv));
            float* op = out + (long)n * DD + t * 8;
            *(float4*)op = o0;
            *(float4*)(op + 4) = o1;
        }
    } else {
        if (g == 0) {                          // empty segment: sigmoid(0) = 0.5
            float4 h = make_float4(0.5f, 0.5f, 0.5f, 0.5f);
            float* op = out + (long)n * DD + t * 8;
            *(float4*)op = h;
            *(float4*)(op + 4) = h;
        }
    }
}

extern "C" void kernel_launch(void* const* d_in, const int* in_sizes, int n_in,
                              void* d_out, int out_size, void* d_ws, size_t ws_size,
                              hipStream_t stream) {
    const int*   edge    = (const int*)d_in[0];
    const float* emb     = (const float*)d_in[1];
    const float* W_scale = (const float*)d_in[2];
    const float* b_scale = (const float*)d_in[3];
    const float* W_att   = (const float*)d_in[4];
    const float* b_att   = (const float*)d_in[5];
    float* out = (float*)d_out;

    char* ws = (char*)d_ws;
    unsigned short* WT      = (unsigned short*)(ws);                     // 32 KB
    int*            row_ptr = (int*)(ws + 32768);                        // 200832 B
    float*          a_src   = (float*)(ws + 32768 + 200832);             // 200192 B
    float*          a_dst   = (float*)(ws + 32768 + 200832 + 200192);    // 200192 B
    unsigned short* item    = (unsigned short*)(ws + 32768 + 200832 + 2 * 200192); // 12.8 MB

    int node_blocks = (NN + 3) / 4;          // wave per node, 4 waves/block
    int tile_blocks = ((NN + 15) / 16 + 3) / 4;
    int edge_blocks = (NE + 255) / 256;

    k_wt    <<<64,          256, 0, stream>>>(W_scale, WT);
    k_rowptr<<<edge_blocks, 256, 0, stream>>>(edge, row_ptr);
    k_gemm  <<<tile_blocks, 256, 0, stream>>>(emb, WT, b_scale, W_att, item, a_src, a_dst);
    k_agg   <<<node_blocks, 256, 0, stream>>>(edge, row_ptr, item, a_src, a_dst, b_att, out);
}

// Round 3
// 146.322 us; speedup vs baseline: 1.6903x; 1.0179x over previous
//
#include <hip/hip_runtime.h>
#include <math.h>

#define NN 50001
#define DD 128
#define NE 800000

typedef __attribute__((ext_vector_type(8))) short short8;
typedef __attribute__((ext_vector_type(4))) float floatx4;

__device__ __forceinline__ unsigned short f2bf(float f) {
    unsigned u = __builtin_bit_cast(unsigned, f);
    u += 0x7fffu + ((u >> 16) & 1u);          // round-to-nearest-even
    return (unsigned short)(u >> 16);
}
__device__ __forceinline__ float bflo(unsigned u) {   // low 16 bits as bf16 -> f32
    return __builtin_bit_cast(float, u << 16);
}
__device__ __forceinline__ float bfhi(unsigned u) {   // high 16 bits as bf16 -> f32
    return __builtin_bit_cast(float, u & 0xffff0000u);
}

// K0: blocks 0..63: W_scale (128x128 f32,[k][j]) -> WT bf16 [j][k].
//     blocks 64.. : row_ptr[n] = first edge e with src[e] >= n (src sorted).
__global__ void k_prep(const float* __restrict__ W, unsigned short* __restrict__ WT,
                       const int* __restrict__ edge, int* __restrict__ row_ptr) {
    int b = blockIdx.x;
    if (b < 64) {
        int idx = b * 256 + threadIdx.x;
        int k = idx >> 7, j = idx & 127;
        WT[j * DD + k] = f2bf(W[idx]);
    } else {
        int e = (b - 64) * 256 + threadIdx.x;
        if (e >= NE) return;
        int s = edge[2 * e];
        if (e == 0) {
            for (int n = 0; n <= s; n++) row_ptr[n] = 0;
        } else {
            int p = edge[2 * (e - 1)];
            for (int n = p + 1; n <= s; n++) row_ptr[n] = e;
        }
        if (e == NE - 1) {
            for (int n = s + 1; n <= NN; n++) row_ptr[n] = NE;
        }
    }
}

// K1: item = emb @ W_scale + b_scale (bf16 out), fused a_src/a_dst = item . W_att halves.
// One wave per 16-node tile.
__global__ void __launch_bounds__(256) k_gemm(const float* __restrict__ emb,
        const unsigned short* __restrict__ WT, const float* __restrict__ b_scale,
        const float* __restrict__ W_att, unsigned short* __restrict__ item,
        float* __restrict__ a_src, float* __restrict__ a_dst) {
    int wave = blockIdx.x * 4 + (threadIdx.x >> 6);
    int lane = threadIdx.x & 63;
    int base = wave * 16;
    if (base >= NN) return;
    int m = lane & 15, q = lane >> 4;

    // A frags: lane holds A[m][q*8 + ks*32 .. +7], f32 -> bf16 on the fly
    int row = base + m; if (row >= NN) row = NN - 1;
    const float* ap = emb + (long)row * DD + q * 8;
    short8 a[4];
    #pragma unroll
    for (int ks = 0; ks < 4; ks++) {
        float4 f0 = *(const float4*)(ap + ks * 32);
        float4 f1 = *(const float4*)(ap + ks * 32 + 4);
        a[ks][0] = (short)f2bf(f0.x); a[ks][1] = (short)f2bf(f0.y);
        a[ks][2] = (short)f2bf(f0.z); a[ks][3] = (short)f2bf(f0.w);
        a[ks][4] = (short)f2bf(f1.x); a[ks][5] = (short)f2bf(f1.y);
        a[ks][6] = (short)f2bf(f1.z); a[ks][7] = (short)f2bf(f1.w);
    }

    float p_src[4] = {0.f, 0.f, 0.f, 0.f};
    float p_dst[4] = {0.f, 0.f, 0.f, 0.f};

    #pragma unroll
    for (int ft = 0; ft < 8; ft++) {
        int col = ft * 16 + m;
        floatx4 acc = {0.f, 0.f, 0.f, 0.f};
        #pragma unroll
        for (int ks = 0; ks < 4; ks++) {
            short8 b = *(const short8*)(WT + col * DD + ks * 32 + q * 8);
            acc = __builtin_amdgcn_mfma_f32_16x16x32_bf16(a[ks], b, acc, 0, 0, 0);
        }
        float bs = b_scale[col];
        float wsrc = W_att[col], wdst = W_att[DD + col];
        #pragma unroll
        for (int r = 0; r < 4; r++) {
            float v = acc[r] + bs;            // C/D: col = lane&15, row = (lane>>4)*4 + reg
            int gr = base + q * 4 + r;
            if (gr < NN) item[(long)gr * DD + col] = f2bf(v);
            p_src[r] += v * wsrc;
            p_dst[r] += v * wdst;
        }
    }
    // reduce over m (lane bits 0..3): rows stay within the q-group
    #pragma unroll
    for (int off = 1; off <= 8; off <<= 1) {
        #pragma unroll
        for (int r = 0; r < 4; r++) {
            p_src[r] += __shfl_xor(p_src[r], off, 64);
            p_dst[r] += __shfl_xor(p_dst[r], off, 64);
        }
    }
    if (m == 0) {
        #pragma unroll
        for (int r = 0; r < 4; r++) {
            int gr = base + q * 4 + r;
            if (gr < NN) { a_src[gr] = p_src[r]; a_dst[gr] = p_dst[r]; }
        }
    }
}

// K2: edge-parallel scoring -> packed (dst, score) per edge.
__global__ void __launch_bounds__(256) k_score(const int* __restrict__ edge,
        const float* __restrict__ a_src, const float* __restrict__ a_dst,
        const float* __restrict__ b_att, uint2* __restrict__ sd) {
    int e = blockIdx.x * 256 + threadIdx.x;
    if (e >= NE) return;
    int2 ed = ((const int2*)edge)[e];
    float att = a_src[ed.x] + a_dst[ed.y] + b_att[0];
    att = att >= 0.f ? att : 0.2f * att;
    float s = __expf(att - 1.f);
    sd[e] = make_uint2((unsigned)ed.y, __builtin_bit_cast(unsigned, s));
}

// K3: per-node aggregation. One wave per node; lane = 16*g + t.
// Group g owns edges j = g, g+4, g+8, ... ; all 16 lanes of a group broadcast-load
// the same sd[] entry (no shfl), then gather 16 B of item at feature t*8.
__global__ void __launch_bounds__(256) k_agg(const int* __restrict__ row_ptr,
        const uint2* __restrict__ sd, const unsigned short* __restrict__ item,
        float* __restrict__ out) {
    int n = blockIdx.x * 4 + (threadIdx.x >> 6);
    int lane = threadIdx.x & 63;
    if (n >= NN) return;
    int g = lane >> 4, t = lane & 15;

    int start = row_ptr[n];
    int len = row_ptr[n + 1] - start;

    if (len > 0) {
        float acc[8] = {0.f, 0.f, 0.f, 0.f, 0.f, 0.f, 0.f, 0.f};
        float ssum = 0.f;
        const uint2* sp = sd + start;
        #pragma unroll 2
        for (int j = g; j < len; j += 4) {
            uint2 p = sp[j];                  // broadcast within the 16-lane group
            float sj = __builtin_bit_cast(float, p.y);
            ssum += sj;
            const uint4 u = *(const uint4*)(item + (long)p.x * DD + t * 8);
            acc[0] += sj * bflo(u.x); acc[1] += sj * bfhi(u.x);
            acc[2] += sj * bflo(u.y); acc[3] += sj * bfhi(u.y);
            acc[4] += sj * bflo(u.z); acc[5] += sj * bfhi(u.z);
            acc[6] += sj * bflo(u.w); acc[7] += sj * bfhi(u.w);
        }
        // combine the 4 edge-groups (lane bits 4,5); ssum is group-uniform per lane
        #pragma unroll
        for (int off = 16; off <= 32; off <<= 1) {
            #pragma unroll
            for (int k = 0; k < 8; k++) acc[k] += __shfl_xor(acc[k], off, 64);
            ssum += __shfl_xor(ssum, off, 64);
        }
        float inv = 1.f / ssum;
        float4 o;
        if (g == 0) {
            o.x = 1.f / (1.f + __expf(-acc[0] * inv));
            o.y = 1.f / (1.f + __expf(-acc[1] * inv));
            o.z = 1.f / (1.f + __expf(-acc[2] * inv));
            o.w = 1.f / (1.f + __expf(-acc[3] * inv));
            *(float4*)(out + (long)n * DD + t * 8) = o;
        } else if (g == 1) {
            o.x = 1.f / (1.f + __expf(-acc[4] * inv));
            o.y = 1.f / (1.f + __expf(-acc[5] * inv));
            o.z = 1.f / (1.f + __expf(-acc[6] * inv));
            o.w = 1.f / (1.f + __expf(-acc[7] * inv));
            *(float4*)(out + (long)n * DD + t * 8 + 4) = o;
        }
    } else {
        float4 h = make_float4(0.5f, 0.5f, 0.5f, 0.5f);   // sigmoid(0)
        if (g == 0)      *(float4*)(out + (long)n * DD + t * 8) = h;
        else if (g == 1) *(float4*)(out + (long)n * DD + t * 8 + 4) = h;
    }
}

extern "C" void kernel_launch(void* const* d_in, const int* in_sizes, int n_in,
                              void* d_out, int out_size, void* d_ws, size_t ws_size,
                              hipStream_t stream) {
    const int*   edge    = (const int*)d_in[0];
    const float* emb     = (const float*)d_in[1];
    const float* W_scale = (const float*)d_in[2];
    const float* b_scale = (const float*)d_in[3];
    const float* W_att   = (const float*)d_in[4];
    const float* b_att   = (const float*)d_in[5];
    float* out = (float*)d_out;

    char* ws = (char*)d_ws;
    unsigned short* WT      = (unsigned short*)(ws);                     // 32768 B
    int*            row_ptr = (int*)(ws + 32768);                        // 200832 B
    float*          a_src   = (float*)(ws + 233600);                     // 200192 B
    float*          a_dst   = (float*)(ws + 433792);                     // 200192 B
    unsigned short* item    = (unsigned short*)(ws + 633984);            // 12800256 B
    uint2*          sd      = (uint2*)(ws + 13434240);                   // 6400000 B

    int node_blocks = (NN + 3) / 4;          // wave per node, 4 waves/block
    int tile_blocks = ((NN + 15) / 16 + 3) / 4;
    int edge_blocks = (NE + 255) / 256;

    k_prep <<<64 + edge_blocks, 256, 0, stream>>>(W_scale, WT, edge, row_ptr);
    k_gemm <<<tile_blocks,      256, 0, stream>>>(emb, WT, b_scale, W_att, item, a_src, a_dst);
    k_score<<<edge_blocks,      256, 0, stream>>>(edge, a_src, a_dst, b_att, sd);
    k_agg  <<<node_blocks,      256, 0, stream>>>(row_ptr, sd, item, out);
}